// Round 8
// baseline (321.090 us; speedup 1.0000x reference)
//
#include <hip/hip_runtime.h>
#include <hip/hip_bf16.h>
#include <cstdint>

typedef unsigned short u16;
typedef __attribute__((ext_vector_type(8))) short s16x8;
typedef __attribute__((ext_vector_type(4))) float f32x4;
typedef __attribute__((ext_vector_type(16))) float f32x16;
typedef __attribute__((ext_vector_type(4))) unsigned int u32x4;
typedef __attribute__((ext_vector_type(2))) unsigned int u32x2;
typedef __attribute__((ext_vector_type(4))) u16 u16x4;

#define LOG2E 1.44269504088896340736f

__device__ __forceinline__ u16 f2b(float f) {
  union { float f; unsigned u; } v; v.f = f;
  unsigned r = v.u + 0x7FFF + ((v.u >> 16) & 1);
  return (u16)(r >> 16);
}

__device__ __forceinline__ void gload_lds16(const u16* g, u16* l) {
  __builtin_amdgcn_global_load_lds((const __attribute__((address_space(1))) void*)g,
                                   (__attribute__((address_space(3))) void*)l, 16, 0, 0);
}

// ---------------- elementwise converts ----------------
__global__ void cvt_bf16(const float* __restrict__ in, u16* __restrict__ out, int n) {
  int i = blockIdx.x * blockDim.x + threadIdx.x;
  if (i < n) out[i] = f2b(in[i]);
}

__global__ void trig_tab(const float* __restrict__ f, float* __restrict__ c,
                         float* __restrict__ s, int n) {
  int i = blockIdx.x * blockDim.x + threadIdx.x;
  if (i < n) { c[i] = cosf(f[i]); s[i] = sinf(f[i]); }
}

// ---------------- GEMM: C[M,N] = A[M,K] * B[N,K]^T (bf16 in, f32 out) ----------------
__global__ __launch_bounds__(256) void gemm_bt(const u16* __restrict__ A, const u16* __restrict__ B,
                                               float* __restrict__ C, int M, int N, int K) {
  __shared__ u16 sA[128 * 64];
  __shared__ u16 sB[128 * 64];
  const int nbn = N >> 7;
  int bx = blockIdx.x % nbn, by = blockIdx.x / nbn;
  int tid = threadIdx.x, w = tid >> 6, lane = tid & 63;
  int wr = (w >> 1) * 64, wc = (w & 1) * 64;
  int lr = lane >> 3, lc = lane & 7;
  f32x4 acc[4][4] = {};
  size_t arow = (size_t)(by * 128) * K;
  size_t brow = (size_t)(bx * 128) * K;
  for (int k0 = 0; k0 < K; k0 += 64) {
    __syncthreads();
    for (int c = 0; c < 4; ++c) {
      int r = w * 32 + c * 8;
      gload_lds16(A + arow + (size_t)(r + lr) * K + k0 + lc * 8, &sA[r * 64]);
      gload_lds16(B + brow + (size_t)(r + lr) * K + k0 + lc * 8, &sB[r * 64]);
    }
    __syncthreads();
    for (int kk = 0; kk < 64; kk += 32) {
      s16x8 af[4], bf[4];
      int ro = lane & 15, ko = kk + (lane >> 4) * 8;
      for (int m = 0; m < 4; ++m) af[m] = *(const s16x8*)&sA[(wr + m * 16 + ro) * 64 + ko];
      for (int n = 0; n < 4; ++n) bf[n] = *(const s16x8*)&sB[(wc + n * 16 + ro) * 64 + ko];
      for (int m = 0; m < 4; ++m)
        for (int n = 0; n < 4; ++n)
          acc[m][n] = __builtin_amdgcn_mfma_f32_16x16x32_bf16(af[m], bf[n], acc[m][n], 0, 0, 0);
    }
  }
  int ro = lane & 15, rg = lane >> 4;
  for (int m = 0; m < 4; ++m)
    for (int n = 0; n < 4; ++n) {
      int row = by * 128 + wr + m * 16 + rg * 4;
      int col = bx * 128 + wc + n * 16 + ro;
      float* cp = C + (size_t)row * N + col;
      for (int r = 0; r < 4; ++r) cp[(size_t)r * N] = acc[m][n][r];
    }
}

// ---------------- fused per-head LayerNorm + RoPE ----------------
__global__ __launch_bounds__(256) void ln_rope(const float* __restrict__ qkv,
    const float* __restrict__ cosT, const float* __restrict__ sinT,
    const float* __restrict__ qg, const float* __restrict__ qb,
    const float* __restrict__ kg, const float* __restrict__ kb,
    u16* __restrict__ qo, u16* __restrict__ ko, u16* __restrict__ vo) {
  int gw = (blockIdx.x * 256 + threadIdx.x) >> 6;
  int lane = threadIdx.x & 63;
  int h = gw & 15, bs = gw >> 4;
  int s = bs & 2047, b = bs >> 11;
  const float* row = qkv + (size_t)bs * 3072;
  float qv = row[h * 64 + lane];
  float kv = row[1024 + h * 64 + lane];
  float vv = row[2048 + h * 64 + lane];

  float s1q = qv, s2q = qv * qv, s1k = kv, s2k = kv * kv;
  for (int off = 1; off < 64; off <<= 1) {
    s1q += __shfl_xor(s1q, off, 64); s2q += __shfl_xor(s2q, off, 64);
    s1k += __shfl_xor(s1k, off, 64); s2k += __shfl_xor(s2k, off, 64);
  }
  float muq = s1q * (1.f / 64.f), varq = s2q * (1.f / 64.f) - muq * muq;
  float muk = s1k * (1.f / 64.f), vark = s2k * (1.f / 64.f) - muk * muk;
  float qn = (qv - muq) * rsqrtf(varq + 1e-6f) * qg[lane] + qb[lane];
  float kn = (kv - muk) * rsqrtf(vark + 1e-6f) * kg[lane] + kb[lane];

  float cs = cosT[s * 64 + lane], sn = sinT[s * 64 + lane];
  float qh = __shfl_xor(qn, 32, 64); qh = (lane < 32) ? -qh : qh;
  float kh = __shfl_xor(kn, 32, 64); kh = (lane < 32) ? -kh : kh;
  float qr = (qn * cs + qh * sn) * 0.125f;
  float kr = kn * cs + kh * sn;

  size_t oidx = ((size_t)((b * 16 + h) * 2048 + s)) * 64 + lane;
  qo[oidx] = f2b(qr); ko[oidx] = f2b(kr); vo[oidx] = f2b(vv);
}

// ---------------- V transpose: (b,h,s,dh) -> (b,h,dh,s) ----------------
__global__ __launch_bounds__(256) void transpose_v(const u16* __restrict__ vi, u16* __restrict__ vt) {
  __shared__ __align__(16) u16 tile[64][72];
  int bh = blockIdx.x >> 5, st = blockIdx.x & 31;
  int t = threadIdx.x;
  const u16* src = vi + ((size_t)bh * 2048 + st * 64) * 64;
  int r = t & 63, c = (t >> 6) * 16;
  *(s16x8*)&tile[r][c]     = *(const s16x8*)(src + r * 64 + c);
  *(s16x8*)&tile[r][c + 8] = *(const s16x8*)(src + r * 64 + c + 8);
  __syncthreads();
  int dh = t & 63, so = (t >> 6) * 16;
  alignas(16) u16 buf[16];
  #pragma unroll
  for (int j = 0; j < 16; ++j) buf[j] = tile[so + j][dh];
  u16* dst = vt + ((size_t)bh * 64 + dh) * 2048 + st * 64 + so;
  *(s16x8*)dst       = *(const s16x8*)&buf[0];
  *(s16x8*)(dst + 8) = *(const s16x8*)&buf[8];
}

// ---------------- causal flash attention: K-split flash-decode ----------------
// Block (4 waves) owns strip-pair {A=pr, B=63-pr}: 65 tile-instances, uniform.
// Wave w handles kt = w, w+4, ...; two independent softmax chains per wave.
// TWO-PASS LSE merge (dh 0..31 then 32..63) through a 32 KB LDS buffer ->
// 34.8 KB/block -> 4 blocks/CU (16 waves/CU, 4/SIMD) for latency hiding.
__global__ __launch_bounds__(256, 4) void attn_fwd5(const u16* __restrict__ qp, const u16* __restrict__ kp,
                                                    const u16* __restrict__ vtp, u16* __restrict__ op) {
  __shared__ float sO[8][32][32];          // [w*2+s][dh(half)][q]  32 KB, reused across passes
  __shared__ float sM[8][32], sL[8][32];   // 2 KB
  int bid = blockIdx.x;
  int xcd = bid & 7, j = bid >> 3;             // 1024 = 8 XCD * 128
  int bh = 4 * xcd + (j >> 5), pr = j & 31;    // each XCD: 4 heads (2 MB K/V, L2-resident)
  int tid = threadIdx.x, w = tid >> 6, l = tid & 63;
  int ql = l & 31, h5 = l >> 5;
  const int A = pr, Bs = 63 - pr;
  int b = bh >> 4, h = bh & 15;
  const u16* qptr = qp + (size_t)bh * 2048 * 64;
  const u16* kptr = kp + (size_t)bh * 2048 * 64;
  const u16* vptr = vtp + (size_t)bh * 64 * 2048;

  s16x8 qfA[4], qfB[4];
  {
    const u16* qrA = qptr + (size_t)(A * 32 + ql) * 64 + h5 * 8;
    const u16* qrB = qptr + (size_t)(Bs * 32 + ql) * 64 + h5 * 8;
    #pragma unroll
    for (int t = 0; t < 4; ++t) { qfA[t] = *(const s16x8*)(qrA + 16 * t);
                                  qfB[t] = *(const s16x8*)(qrB + 16 * t); }
  }
  f32x16 oA0 = {}, oA1 = {}, oB0 = {}, oB1 = {};
  float mA = -INFINITY, lA = 0.f, mB = -INFINITY, lB = 0.f;

  auto tile = [&](const s16x8* qf, float& m, float& lsum, f32x16& o0, f32x16& o1,
                  s16x8 k0, s16x8 k1, s16x8 k2, s16x8 k3,
                  s16x8 v00, s16x8 v01, s16x8 v10, s16x8 v11, int kt, int strip) {
    f32x16 sc = {};
    sc = __builtin_amdgcn_mfma_f32_32x32x16_bf16(k0, qf[0], sc, 0, 0, 0);
    sc = __builtin_amdgcn_mfma_f32_32x32x16_bf16(k1, qf[1], sc, 0, 0, 0);
    sc = __builtin_amdgcn_mfma_f32_32x32x16_bf16(k2, qf[2], sc, 0, 0, 0);
    sc = __builtin_amdgcn_mfma_f32_32x32x16_bf16(k3, qf[3], sc, 0, 0, 0);

    if (kt == strip) {   // diagonal tile: mask k_loc > q_loc
      #pragma unroll
      for (int r = 0; r < 16; ++r) {
        int kloc = (r & 3) + 8 * (r >> 2) + 4 * h5;
        sc[r] = (kloc > ql) ? -INFINITY : sc[r];
      }
    }
    float t8[8], t4[4];
    #pragma unroll
    for (int i = 0; i < 8; ++i) t8[i] = fmaxf(sc[2 * i], sc[2 * i + 1]);
    #pragma unroll
    for (int i = 0; i < 4; ++i) t4[i] = fmaxf(t8[2 * i], t8[2 * i + 1]);
    float mx = fmaxf(fmaxf(t4[0], t4[1]), fmaxf(t4[2], t4[3]));
    mx = fmaxf(mx, __shfl_xor(mx, 32, 64));

    if (__any(mx > m)) {          // exact skip: alpha==1.0 when no lane grows
      float mn = fmaxf(m, mx);
      float alpha = __builtin_amdgcn_exp2f((m - mn) * LOG2E);
      #pragma unroll
      for (int r = 0; r < 16; ++r) { o0[r] *= alpha; o1[r] *= alpha; }
      lsum *= alpha;
      m = mn;
    }
    float rs = 0.f;
    #pragma unroll
    for (int r = 0; r < 16; ++r) {
      float p = __builtin_amdgcn_exp2f((sc[r] - m) * LOG2E);
      sc[r] = p; rs += p;
    }
    rs += __shfl_xor(rs, 32, 64);
    lsum += rs;

    unsigned wd[8];
    #pragma unroll
    for (int i = 0; i < 8; ++i)
      asm("v_cvt_pk_bf16_f32 %0, %1, %2" : "=v"(wd[i]) : "v"(sc[2 * i]), "v"(sc[2 * i + 1]));
    u32x2 r02 = __builtin_amdgcn_permlane32_swap(wd[0], wd[2], false, false);
    u32x2 r13 = __builtin_amdgcn_permlane32_swap(wd[1], wd[3], false, false);
    u32x2 r46 = __builtin_amdgcn_permlane32_swap(wd[4], wd[6], false, false);
    u32x2 r57 = __builtin_amdgcn_permlane32_swap(wd[5], wd[7], false, false);
    u32x4 t0v = {r02[0], r13[0], r02[1], r13[1]};
    u32x4 t1v = {r46[0], r57[0], r46[1], r57[1]};
    s16x8 pa0 = __builtin_bit_cast(s16x8, t0v);
    s16x8 pa1 = __builtin_bit_cast(s16x8, t1v);

    o0 = __builtin_amdgcn_mfma_f32_32x32x16_bf16(v00, pa0, o0, 0, 0, 0);
    o0 = __builtin_amdgcn_mfma_f32_32x32x16_bf16(v01, pa1, o0, 0, 0, 0);
    o1 = __builtin_amdgcn_mfma_f32_32x32x16_bf16(v10, pa0, o1, 0, 0, 0);
    o1 = __builtin_amdgcn_mfma_f32_32x32x16_bf16(v11, pa1, o1, 0, 0, 0);
  };

  for (int kt = w; kt <= Bs; kt += 4) {
    const u16* kr = kptr + (size_t)(kt * 32 + ql) * 64 + h5 * 8;
    s16x8 k0 = *(const s16x8*)(kr);
    s16x8 k1 = *(const s16x8*)(kr + 16);
    s16x8 k2 = *(const s16x8*)(kr + 32);
    s16x8 k3 = *(const s16x8*)(kr + 48);
    const u16* vr = vptr + (size_t)ql * 2048 + kt * 32 + h5 * 8;
    s16x8 v00 = *(const s16x8*)(vr);
    s16x8 v01 = *(const s16x8*)(vr + 16);
    s16x8 v10 = *(const s16x8*)(vr + 32 * 2048);
    s16x8 v11 = *(const s16x8*)(vr + 32 * 2048 + 16);

    tile(qfB, mB, lB, oB0, oB1, k0, k1, k2, k3, v00, v01, v10, v11, kt, Bs);
    if (kt <= A)
      tile(qfA, mA, lA, oA0, oA1, k0, k1, k2, k3, v00, v01, v10, v11, kt, A);
  }

  // ---- write per-strip m/l once ----
  if (h5 == 0) {
    sM[w * 2 + 0][ql] = mA; sL[w * 2 + 0][ql] = lA;
    sM[w * 2 + 1][ql] = mB; sL[w * 2 + 1][ql] = lB;
  }

  // ---- two-pass merge: pass 0 = dh 0..31 (o*0), pass 1 = dh 32..63 (o*1) ----
  #pragma unroll
  for (int pass = 0; pass < 2; ++pass) {
    const f32x16& pA = pass ? oA1 : oA0;
    const f32x16& pB = pass ? oB1 : oB0;
    if (pass) __syncthreads();            // protect buffer reuse
    #pragma unroll
    for (int r = 0; r < 16; ++r) {
      int dh = (r & 3) + 8 * (r >> 2) + 4 * h5;   // 0..31 within half
      sO[w * 2 + 0][dh][ql] = pA[r];
      sO[w * 2 + 1][dh][ql] = pB[r];
    }
    __syncthreads();
    {
      int q = tid & 31, dq = tid >> 5;    // dq 0..7, each covers 4 dh
      #pragma unroll
      for (int s = 0; s < 2; ++s) {
        float m0 = sM[0 + s][q], m1 = sM[2 + s][q];
        float m2 = sM[4 + s][q], m3 = sM[6 + s][q];
        float mg = fmaxf(fmaxf(m0, m1), fmaxf(m2, m3));
        float e0 = __builtin_amdgcn_exp2f((m0 - mg) * LOG2E);
        float e1 = __builtin_amdgcn_exp2f((m1 - mg) * LOG2E);
        float e2 = __builtin_amdgcn_exp2f((m2 - mg) * LOG2E);
        float e3 = __builtin_amdgcn_exp2f((m3 - mg) * LOG2E);
        float lg = e0 * sL[0 + s][q] + e1 * sL[2 + s][q]
                 + e2 * sL[4 + s][q] + e3 * sL[6 + s][q];
        float inv = 1.f / lg;
        alignas(8) u16 ob[4];
        #pragma unroll
        for (int jj = 0; jj < 4; ++jj) {
          int dh = dq * 4 + jj;
          float acc = e0 * sO[0 + s][dh][q] + e1 * sO[2 + s][dh][q]
                    + e2 * sO[4 + s][dh][q] + e3 * sO[6 + s][dh][q];
          ob[jj] = f2b(acc * inv);
        }
        int q0s = (s ? Bs : A) * 32;
        u16* dst = op + ((size_t)(b * 2048 + q0s + q)) * 1024 + h * 64 + pass * 32 + dq * 4;
        *(u16x4*)dst = *(const u16x4*)&ob[0];
      }
    }
  }
}

extern "C" void kernel_launch(void* const* d_in, const int* in_sizes, int n_in,
                              void* d_out, int out_size, void* d_ws, size_t ws_size,
                              hipStream_t stream) {
  const float* x     = (const float*)d_in[0];
  const float* freqs = (const float*)d_in[2];
  const float* Wqkv  = (const float*)d_in[3];
  const float* Wout  = (const float*)d_in[4];
  const float* qg    = (const float*)d_in[5];
  const float* qb    = (const float*)d_in[6];
  const float* kg    = (const float*)d_in[7];
  const float* kb    = (const float*)d_in[8];
  float* out = (float*)d_out;

  u16* xb    = (u16*)d_ws;                 // 4,194,304
  u16* wqkvb = xb + 4194304;               // 3,145,728
  u16* woutb = wqkvb + 3145728;            // 1,048,576
  float* cosT = (float*)(woutb + 1048576); // 131,072 f32
  float* sinT = cosT + 131072;
  float* qkv  = sinT + 131072;             // 12,582,912 f32
  u16* qo = (u16*)(qkv + 12582912);        // 4,194,304 each
  u16* ko = qo + 4194304;
  u16* vo = ko + 4194304;
  u16* ao = vo + 4194304;
  u16* vt = (u16*)qkv;                     // aliases qkv (dead after ln_rope)

  cvt_bf16<<<(4194304 + 255) / 256, 256, 0, stream>>>(x, xb, 4194304);
  cvt_bf16<<<(3145728 + 255) / 256, 256, 0, stream>>>(Wqkv, wqkvb, 3145728);
  cvt_bf16<<<(1048576 + 255) / 256, 256, 0, stream>>>(Wout, woutb, 1048576);
  trig_tab<<<(131072 + 255) / 256, 256, 0, stream>>>(freqs, cosT, sinT, 131072);

  gemm_bt<<<(4096 / 128) * (3072 / 128), 256, 0, stream>>>(xb, wqkvb, qkv, 4096, 3072, 1024);
  ln_rope<<<65536 / 4, 256, 0, stream>>>(qkv, cosT, sinT, qg, qb, kg, kb, qo, ko, vo);
  transpose_v<<<32 * 32, 256, 0, stream>>>(vo, vt);
  attn_fwd5<<<1024, 256, 0, stream>>>(qo, ko, vt, ao);
  gemm_bt<<<(4096 / 128) * (1024 / 128), 256, 0, stream>>>(ao, woutb, out, 4096, 1024, 1024);
}

// Round 9
// 261.566 us; speedup vs baseline: 1.2276x; 1.2276x over previous
//
#include <hip/hip_runtime.h>
#include <hip/hip_bf16.h>
#include <cstdint>

typedef unsigned short u16;
typedef __attribute__((ext_vector_type(8))) short s16x8;
typedef __attribute__((ext_vector_type(4))) float f32x4;
typedef __attribute__((ext_vector_type(16))) float f32x16;
typedef __attribute__((ext_vector_type(4))) unsigned int u32x4;
typedef __attribute__((ext_vector_type(2))) unsigned int u32x2;
typedef __attribute__((ext_vector_type(4))) u16 u16x4;

#define LOG2E 1.44269504088896340736f

__device__ __forceinline__ u16 f2b(float f) {
  union { float f; unsigned u; } v; v.f = f;
  unsigned r = v.u + 0x7FFF + ((v.u >> 16) & 1);
  return (u16)(r >> 16);
}

__device__ __forceinline__ float b2f(u16 u) {
  union { unsigned u; float f; } v; v.u = ((unsigned)u) << 16;
  return v.f;
}

__device__ __forceinline__ void gload_lds16(const u16* g, u16* l) {
  __builtin_amdgcn_global_load_lds((const __attribute__((address_space(1))) void*)g,
                                   (__attribute__((address_space(3))) void*)l, 16, 0, 0);
}

// ---------------- elementwise converts ----------------
__global__ void cvt_bf16(const float* __restrict__ in, u16* __restrict__ out, int n) {
  int i = blockIdx.x * blockDim.x + threadIdx.x;
  if (i < n) out[i] = f2b(in[i]);
}

__global__ void trig_tab(const float* __restrict__ f, float* __restrict__ c,
                         float* __restrict__ s, int n) {
  int i = blockIdx.x * blockDim.x + threadIdx.x;
  if (i < n) { c[i] = cosf(f[i]); s[i] = sinf(f[i]); }
}

// ---------------- GEMM: C[M,N] = A[M,K] * B[N,K]^T (bf16 in, f32 out) ----------------
__global__ __launch_bounds__(256) void gemm_bt(const u16* __restrict__ A, const u16* __restrict__ B,
                                               float* __restrict__ C, int M, int N, int K) {
  __shared__ u16 sA[128 * 64];
  __shared__ u16 sB[128 * 64];
  const int nbn = N >> 7;
  int bx = blockIdx.x % nbn, by = blockIdx.x / nbn;
  int tid = threadIdx.x, w = tid >> 6, lane = tid & 63;
  int wr = (w >> 1) * 64, wc = (w & 1) * 64;
  int lr = lane >> 3, lc = lane & 7;
  f32x4 acc[4][4] = {};
  size_t arow = (size_t)(by * 128) * K;
  size_t brow = (size_t)(bx * 128) * K;
  for (int k0 = 0; k0 < K; k0 += 64) {
    __syncthreads();
    for (int c = 0; c < 4; ++c) {
      int r = w * 32 + c * 8;
      gload_lds16(A + arow + (size_t)(r + lr) * K + k0 + lc * 8, &sA[r * 64]);
      gload_lds16(B + brow + (size_t)(r + lr) * K + k0 + lc * 8, &sB[r * 64]);
    }
    __syncthreads();
    for (int kk = 0; kk < 64; kk += 32) {
      s16x8 af[4], bf[4];
      int ro = lane & 15, ko = kk + (lane >> 4) * 8;
      for (int m = 0; m < 4; ++m) af[m] = *(const s16x8*)&sA[(wr + m * 16 + ro) * 64 + ko];
      for (int n = 0; n < 4; ++n) bf[n] = *(const s16x8*)&sB[(wc + n * 16 + ro) * 64 + ko];
      for (int m = 0; m < 4; ++m)
        for (int n = 0; n < 4; ++n)
          acc[m][n] = __builtin_amdgcn_mfma_f32_16x16x32_bf16(af[m], bf[n], acc[m][n], 0, 0, 0);
    }
  }
  int ro = lane & 15, rg = lane >> 4;
  for (int m = 0; m < 4; ++m)
    for (int n = 0; n < 4; ++n) {
      int row = by * 128 + wr + m * 16 + rg * 4;
      int col = bx * 128 + wc + n * 16 + ro;
      float* cp = C + (size_t)row * N + col;
      for (int r = 0; r < 4; ++r) cp[(size_t)r * N] = acc[m][n][r];
    }
}

// ---------------- fused per-head LayerNorm + RoPE ----------------
__global__ __launch_bounds__(256) void ln_rope(const float* __restrict__ qkv,
    const float* __restrict__ cosT, const float* __restrict__ sinT,
    const float* __restrict__ qg, const float* __restrict__ qb,
    const float* __restrict__ kg, const float* __restrict__ kb,
    u16* __restrict__ qo, u16* __restrict__ ko, u16* __restrict__ vo) {
  int gw = (blockIdx.x * 256 + threadIdx.x) >> 6;
  int lane = threadIdx.x & 63;
  int h = gw & 15, bs = gw >> 4;
  int s = bs & 2047, b = bs >> 11;
  const float* row = qkv + (size_t)bs * 3072;
  float qv = row[h * 64 + lane];
  float kv = row[1024 + h * 64 + lane];
  float vv = row[2048 + h * 64 + lane];

  float s1q = qv, s2q = qv * qv, s1k = kv, s2k = kv * kv;
  for (int off = 1; off < 64; off <<= 1) {
    s1q += __shfl_xor(s1q, off, 64); s2q += __shfl_xor(s2q, off, 64);
    s1k += __shfl_xor(s1k, off, 64); s2k += __shfl_xor(s2k, off, 64);
  }
  float muq = s1q * (1.f / 64.f), varq = s2q * (1.f / 64.f) - muq * muq;
  float muk = s1k * (1.f / 64.f), vark = s2k * (1.f / 64.f) - muk * muk;
  float qn = (qv - muq) * rsqrtf(varq + 1e-6f) * qg[lane] + qb[lane];
  float kn = (kv - muk) * rsqrtf(vark + 1e-6f) * kg[lane] + kb[lane];

  float cs = cosT[s * 64 + lane], sn = sinT[s * 64 + lane];
  float qh = __shfl_xor(qn, 32, 64); qh = (lane < 32) ? -qh : qh;
  float kh = __shfl_xor(kn, 32, 64); kh = (lane < 32) ? -kh : kh;
  float qr = (qn * cs + qh * sn) * 0.125f;
  float kr = kn * cs + kh * sn;

  size_t oidx = ((size_t)((b * 16 + h) * 2048 + s)) * 64 + lane;
  qo[oidx] = f2b(qr); ko[oidx] = f2b(kr); vo[oidx] = f2b(vv);
}

// ---------------- V transpose: (b,h,s,dh) -> (b,h,dh,s) ----------------
__global__ __launch_bounds__(256) void transpose_v(const u16* __restrict__ vi, u16* __restrict__ vt) {
  __shared__ __align__(16) u16 tile[64][72];
  int bh = blockIdx.x >> 5, st = blockIdx.x & 31;
  int t = threadIdx.x;
  const u16* src = vi + ((size_t)bh * 2048 + st * 64) * 64;
  int r = t & 63, c = (t >> 6) * 16;
  *(s16x8*)&tile[r][c]     = *(const s16x8*)(src + r * 64 + c);
  *(s16x8*)&tile[r][c + 8] = *(const s16x8*)(src + r * 64 + c + 8);
  __syncthreads();
  int dh = t & 63, so = (t >> 6) * 16;
  alignas(16) u16 buf[16];
  #pragma unroll
  for (int j = 0; j < 16; ++j) buf[j] = tile[so + j][dh];
  u16* dst = vt + ((size_t)bh * 64 + dh) * 2048 + st * 64 + so;
  *(s16x8*)dst       = *(const s16x8*)&buf[0];
  *(s16x8*)(dst + 8) = *(const s16x8*)&buf[8];
}

// ---------------- causal flash attention: K-split flash-decode ----------------
// Block (4 waves) owns strip-pair {A=pr, B=63-pr}: 65 tile-instances, uniform.
// Wave w handles kt = w, w+4, ...; two independent softmax chains per wave.
// ONE-PASS merge (accumulators die at staging writes -> no spills), partials
// staged in BF16: LDS 34.8 KB -> 4 blocks/CU (16 waves/CU, 4/SIMD).
__global__ __launch_bounds__(256) void attn_fwd6(const u16* __restrict__ qp, const u16* __restrict__ kp,
                                                 const u16* __restrict__ vtp, u16* __restrict__ op) {
  __shared__ u16 sO[8][64][32];            // [w*2+s][dh][q]  bf16, 32 KB
  __shared__ float sM[8][32], sL[8][32];   // 2 KB
  int bid = blockIdx.x;
  int xcd = bid & 7, j = bid >> 3;             // 1024 = 8 XCD * 128
  int bh = 4 * xcd + (j >> 5), pr = j & 31;    // each XCD: 4 heads (2 MB K/V, L2-resident)
  int tid = threadIdx.x, w = tid >> 6, l = tid & 63;
  int ql = l & 31, h5 = l >> 5;
  const int A = pr, Bs = 63 - pr;
  int b = bh >> 4, h = bh & 15;
  const u16* qptr = qp + (size_t)bh * 2048 * 64;
  const u16* kptr = kp + (size_t)bh * 2048 * 64;
  const u16* vptr = vtp + (size_t)bh * 64 * 2048;

  s16x8 qfA[4], qfB[4];
  {
    const u16* qrA = qptr + (size_t)(A * 32 + ql) * 64 + h5 * 8;
    const u16* qrB = qptr + (size_t)(Bs * 32 + ql) * 64 + h5 * 8;
    #pragma unroll
    for (int t = 0; t < 4; ++t) { qfA[t] = *(const s16x8*)(qrA + 16 * t);
                                  qfB[t] = *(const s16x8*)(qrB + 16 * t); }
  }
  f32x16 oA0 = {}, oA1 = {}, oB0 = {}, oB1 = {};
  float mA = -INFINITY, lA = 0.f, mB = -INFINITY, lB = 0.f;

  auto tile = [&](const s16x8* qf, float& m, float& lsum, f32x16& o0, f32x16& o1,
                  s16x8 k0, s16x8 k1, s16x8 k2, s16x8 k3,
                  s16x8 v00, s16x8 v01, s16x8 v10, s16x8 v11, int kt, int strip) {
    f32x16 sc = {};
    sc = __builtin_amdgcn_mfma_f32_32x32x16_bf16(k0, qf[0], sc, 0, 0, 0);
    sc = __builtin_amdgcn_mfma_f32_32x32x16_bf16(k1, qf[1], sc, 0, 0, 0);
    sc = __builtin_amdgcn_mfma_f32_32x32x16_bf16(k2, qf[2], sc, 0, 0, 0);
    sc = __builtin_amdgcn_mfma_f32_32x32x16_bf16(k3, qf[3], sc, 0, 0, 0);

    if (kt == strip) {   // diagonal tile: mask k_loc > q_loc
      #pragma unroll
      for (int r = 0; r < 16; ++r) {
        int kloc = (r & 3) + 8 * (r >> 2) + 4 * h5;
        sc[r] = (kloc > ql) ? -INFINITY : sc[r];
      }
    }
    float t8[8], t4[4];
    #pragma unroll
    for (int i = 0; i < 8; ++i) t8[i] = fmaxf(sc[2 * i], sc[2 * i + 1]);
    #pragma unroll
    for (int i = 0; i < 4; ++i) t4[i] = fmaxf(t8[2 * i], t8[2 * i + 1]);
    float mx = fmaxf(fmaxf(t4[0], t4[1]), fmaxf(t4[2], t4[3]));
    mx = fmaxf(mx, __shfl_xor(mx, 32, 64));

    if (__any(mx > m)) {          // exact skip: alpha==1.0 when no lane grows
      float mn = fmaxf(m, mx);
      float alpha = __builtin_amdgcn_exp2f((m - mn) * LOG2E);
      #pragma unroll
      for (int r = 0; r < 16; ++r) { o0[r] *= alpha; o1[r] *= alpha; }
      lsum *= alpha;
      m = mn;
    }
    float rs = 0.f;
    #pragma unroll
    for (int r = 0; r < 16; ++r) {
      float p = __builtin_amdgcn_exp2f((sc[r] - m) * LOG2E);
      sc[r] = p; rs += p;
    }
    rs += __shfl_xor(rs, 32, 64);
    lsum += rs;

    unsigned wd[8];
    #pragma unroll
    for (int i = 0; i < 8; ++i)
      asm("v_cvt_pk_bf16_f32 %0, %1, %2" : "=v"(wd[i]) : "v"(sc[2 * i]), "v"(sc[2 * i + 1]));
    u32x2 r02 = __builtin_amdgcn_permlane32_swap(wd[0], wd[2], false, false);
    u32x2 r13 = __builtin_amdgcn_permlane32_swap(wd[1], wd[3], false, false);
    u32x2 r46 = __builtin_amdgcn_permlane32_swap(wd[4], wd[6], false, false);
    u32x2 r57 = __builtin_amdgcn_permlane32_swap(wd[5], wd[7], false, false);
    u32x4 t0v = {r02[0], r13[0], r02[1], r13[1]};
    u32x4 t1v = {r46[0], r57[0], r46[1], r57[1]};
    s16x8 pa0 = __builtin_bit_cast(s16x8, t0v);
    s16x8 pa1 = __builtin_bit_cast(s16x8, t1v);

    o0 = __builtin_amdgcn_mfma_f32_32x32x16_bf16(v00, pa0, o0, 0, 0, 0);
    o0 = __builtin_amdgcn_mfma_f32_32x32x16_bf16(v01, pa1, o0, 0, 0, 0);
    o1 = __builtin_amdgcn_mfma_f32_32x32x16_bf16(v10, pa0, o1, 0, 0, 0);
    o1 = __builtin_amdgcn_mfma_f32_32x32x16_bf16(v11, pa1, o1, 0, 0, 0);
  };

  for (int kt = w; kt <= Bs; kt += 4) {
    const u16* kr = kptr + (size_t)(kt * 32 + ql) * 64 + h5 * 8;
    s16x8 k0 = *(const s16x8*)(kr);
    s16x8 k1 = *(const s16x8*)(kr + 16);
    s16x8 k2 = *(const s16x8*)(kr + 32);
    s16x8 k3 = *(const s16x8*)(kr + 48);
    const u16* vr = vptr + (size_t)ql * 2048 + kt * 32 + h5 * 8;
    s16x8 v00 = *(const s16x8*)(vr);
    s16x8 v01 = *(const s16x8*)(vr + 16);
    s16x8 v10 = *(const s16x8*)(vr + 32 * 2048);
    s16x8 v11 = *(const s16x8*)(vr + 32 * 2048 + 16);

    tile(qfB, mB, lB, oB0, oB1, k0, k1, k2, k3, v00, v01, v10, v11, kt, Bs);
    if (kt <= A)
      tile(qfA, mA, lA, oA0, oA1, k0, k1, k2, k3, v00, v01, v10, v11, kt, A);
  }

  // ---- write partials (bf16 staging; accumulators die here) ----
  if (h5 == 0) {
    sM[w * 2 + 0][ql] = mA; sL[w * 2 + 0][ql] = lA;
    sM[w * 2 + 1][ql] = mB; sL[w * 2 + 1][ql] = lB;
  }
  #pragma unroll
  for (int r = 0; r < 16; ++r) {
    int dh = (r & 3) + 8 * (r >> 2) + 4 * h5;
    sO[w * 2 + 0][dh][ql]      = f2b(oA0[r]);
    sO[w * 2 + 0][dh + 32][ql] = f2b(oA1[r]);
    sO[w * 2 + 1][dh][ql]      = f2b(oB0[r]);
    sO[w * 2 + 1][dh + 32][ql] = f2b(oB1[r]);
  }
  __syncthreads();

  // ---- LSE merge + output: thread t handles q = t&31, dh = (t>>5)*8 .. +7 ----
  {
    int q = tid & 31, dg = tid >> 5;   // dg 0..7
    #pragma unroll
    for (int s = 0; s < 2; ++s) {
      float m0 = sM[0 * 2 + s][q], m1 = sM[1 * 2 + s][q];
      float m2 = sM[2 * 2 + s][q], m3 = sM[3 * 2 + s][q];
      float mg = fmaxf(fmaxf(m0, m1), fmaxf(m2, m3));
      float e0 = __builtin_amdgcn_exp2f((m0 - mg) * LOG2E);
      float e1 = __builtin_amdgcn_exp2f((m1 - mg) * LOG2E);
      float e2 = __builtin_amdgcn_exp2f((m2 - mg) * LOG2E);
      float e3 = __builtin_amdgcn_exp2f((m3 - mg) * LOG2E);
      float lg = e0 * sL[0 * 2 + s][q] + e1 * sL[1 * 2 + s][q]
               + e2 * sL[2 * 2 + s][q] + e3 * sL[3 * 2 + s][q];
      float inv = 1.f / lg;
      alignas(16) u16 ob[8];
      #pragma unroll
      for (int jj = 0; jj < 8; ++jj) {
        int dh = dg * 8 + jj;
        float acc = e0 * b2f(sO[0 * 2 + s][dh][q]) + e1 * b2f(sO[1 * 2 + s][dh][q])
                  + e2 * b2f(sO[2 * 2 + s][dh][q]) + e3 * b2f(sO[3 * 2 + s][dh][q]);
        ob[jj] = f2b(acc * inv);
      }
      int q0s = (s ? Bs : A) * 32;
      u16* dst = op + ((size_t)(b * 2048 + q0s + q)) * 1024 + h * 64 + dg * 8;
      *(u16x4*)dst       = *(const u16x4*)&ob[0];
      *(u16x4*)(dst + 4) = *(const u16x4*)&ob[4];
    }
  }
}

extern "C" void kernel_launch(void* const* d_in, const int* in_sizes, int n_in,
                              void* d_out, int out_size, void* d_ws, size_t ws_size,
                              hipStream_t stream) {
  const float* x     = (const float*)d_in[0];
  const float* freqs = (const float*)d_in[2];
  const float* Wqkv  = (const float*)d_in[3];
  const float* Wout  = (const float*)d_in[4];
  const float* qg    = (const float*)d_in[5];
  const float* qb    = (const float*)d_in[6];
  const float* kg    = (const float*)d_in[7];
  const float* kb    = (const float*)d_in[8];
  float* out = (float*)d_out;

  u16* xb    = (u16*)d_ws;                 // 4,194,304
  u16* wqkvb = xb + 4194304;               // 3,145,728
  u16* woutb = wqkvb + 3145728;            // 1,048,576
  float* cosT = (float*)(woutb + 1048576); // 131,072 f32
  float* sinT = cosT + 131072;
  float* qkv  = sinT + 131072;             // 12,582,912 f32
  u16* qo = (u16*)(qkv + 12582912);        // 4,194,304 each
  u16* ko = qo + 4194304;
  u16* vo = ko + 4194304;
  u16* ao = vo + 4194304;
  u16* vt = (u16*)qkv;                     // aliases qkv (dead after ln_rope)

  cvt_bf16<<<(4194304 + 255) / 256, 256, 0, stream>>>(x, xb, 4194304);
  cvt_bf16<<<(3145728 + 255) / 256, 256, 0, stream>>>(Wqkv, wqkvb, 3145728);
  cvt_bf16<<<(1048576 + 255) / 256, 256, 0, stream>>>(Wout, woutb, 1048576);
  trig_tab<<<(131072 + 255) / 256, 256, 0, stream>>>(freqs, cosT, sinT, 131072);

  gemm_bt<<<(4096 / 128) * (3072 / 128), 256, 0, stream>>>(xb, wqkvb, qkv, 4096, 3072, 1024);
  ln_rope<<<65536 / 4, 256, 0, stream>>>(qkv, cosT, sinT, qg, qb, kg, kb, qo, ko, vo);
  transpose_v<<<32 * 32, 256, 0, stream>>>(vo, vt);
  attn_fwd6<<<1024, 256, 0, stream>>>(qo, ko, vt, ao);
  gemm_bt<<<(4096 / 128) * (1024 / 128), 256, 0, stream>>>(ao, woutb, out, 4096, 1024, 1024);
}

// Round 10
// 253.066 us; speedup vs baseline: 1.2688x; 1.0336x over previous
//
#include <hip/hip_runtime.h>
#include <hip/hip_bf16.h>
#include <cstdint>

typedef unsigned short u16;
typedef __attribute__((ext_vector_type(8))) short s16x8;
typedef __attribute__((ext_vector_type(4))) float f32x4;
typedef __attribute__((ext_vector_type(16))) float f32x16;
typedef __attribute__((ext_vector_type(4))) unsigned int u32x4;
typedef __attribute__((ext_vector_type(2))) unsigned int u32x2;
typedef __attribute__((ext_vector_type(4))) u16 u16x4;

#define LOG2E 1.44269504088896340736f

__device__ __forceinline__ u16 f2b(float f) {
  union { float f; unsigned u; } v; v.f = f;
  unsigned r = v.u + 0x7FFF + ((v.u >> 16) & 1);
  return (u16)(r >> 16);
}

__device__ __forceinline__ float b2f(u16 u) {
  union { unsigned u; float f; } v; v.u = ((unsigned)u) << 16;
  return v.f;
}

__device__ __forceinline__ void gload_lds16(const u16* g, u16* l) {
  __builtin_amdgcn_global_load_lds((const __attribute__((address_space(1))) void*)g,
                                   (__attribute__((address_space(3))) void*)l, 16, 0, 0);
}

// ---------------- elementwise converts ----------------
__global__ void cvt_bf16(const float* __restrict__ in, u16* __restrict__ out, int n) {
  int i = blockIdx.x * blockDim.x + threadIdx.x;
  if (i < n) out[i] = f2b(in[i]);
}

__global__ void trig2_tab(const float* __restrict__ f, float2* __restrict__ t, int n) {
  int i = blockIdx.x * blockDim.x + threadIdx.x;
  if (i < n) { t[i] = make_float2(cosf(f[i]), sinf(f[i])); }
}

// ---------------- GEMM: C[M,N] = A[M,K] * B[N,K]^T (bf16 in, f32 out) ----------------
__global__ __launch_bounds__(256) void gemm_bt(const u16* __restrict__ A, const u16* __restrict__ B,
                                               float* __restrict__ C, int M, int N, int K) {
  __shared__ u16 sA[128 * 64];
  __shared__ u16 sB[128 * 64];
  const int nbn = N >> 7;
  int bx = blockIdx.x % nbn, by = blockIdx.x / nbn;
  int tid = threadIdx.x, w = tid >> 6, lane = tid & 63;
  int wr = (w >> 1) * 64, wc = (w & 1) * 64;
  int lr = lane >> 3, lc = lane & 7;
  f32x4 acc[4][4] = {};
  size_t arow = (size_t)(by * 128) * K;
  size_t brow = (size_t)(bx * 128) * K;
  for (int k0 = 0; k0 < K; k0 += 64) {
    __syncthreads();
    for (int c = 0; c < 4; ++c) {
      int r = w * 32 + c * 8;
      gload_lds16(A + arow + (size_t)(r + lr) * K + k0 + lc * 8, &sA[r * 64]);
      gload_lds16(B + brow + (size_t)(r + lr) * K + k0 + lc * 8, &sB[r * 64]);
    }
    __syncthreads();
    for (int kk = 0; kk < 64; kk += 32) {
      s16x8 af[4], bf[4];
      int ro = lane & 15, ko = kk + (lane >> 4) * 8;
      for (int m = 0; m < 4; ++m) af[m] = *(const s16x8*)&sA[(wr + m * 16 + ro) * 64 + ko];
      for (int n = 0; n < 4; ++n) bf[n] = *(const s16x8*)&sB[(wc + n * 16 + ro) * 64 + ko];
      for (int m = 0; m < 4; ++m)
        for (int n = 0; n < 4; ++n)
          acc[m][n] = __builtin_amdgcn_mfma_f32_16x16x32_bf16(af[m], bf[n], acc[m][n], 0, 0, 0);
    }
  }
  int ro = lane & 15, rg = lane >> 4;
  for (int m = 0; m < 4; ++m)
    for (int n = 0; n < 4; ++n) {
      int row = by * 128 + wr + m * 16 + rg * 4;
      int col = bx * 128 + wc + n * 16 + ro;
      float* cp = C + (size_t)row * N + col;
      for (int r = 0; r < 4; ++r) cp[(size_t)r * N] = acc[m][n][r];
    }
}

// ---------------- fused QKV GEMM + per-head LN + RoPE + bf16 q/k/v write -------------
// M=4096, N=3072, K=1024. Each wave's 64-col tile = exactly one head section;
// LN over dh: 4 in-thread values + shfl_xor{1,2,4,8} within the 16-lane group.
__global__ __launch_bounds__(256) void gemm_qkv_lnrope(
    const u16* __restrict__ A, const u16* __restrict__ B, const float2* __restrict__ trig,
    const float* __restrict__ qg, const float* __restrict__ qb,
    const float* __restrict__ kg, const float* __restrict__ kb,
    u16* __restrict__ qo, u16* __restrict__ ko, u16* __restrict__ vo) {
  const int K = 1024;
  __shared__ u16 sA[128 * 64];
  __shared__ u16 sB[128 * 64];
  int bx = blockIdx.x % 24, by = blockIdx.x / 24;
  int tid = threadIdx.x, w = tid >> 6, lane = tid & 63;
  int wr = (w >> 1) * 64, wc = (w & 1) * 64;
  int lr = lane >> 3, lc = lane & 7;
  f32x4 acc[4][4] = {};
  size_t arow = (size_t)(by * 128) * K;
  size_t brow = (size_t)(bx * 128) * K;
  for (int k0 = 0; k0 < K; k0 += 64) {
    __syncthreads();
    for (int c = 0; c < 4; ++c) {
      int r = w * 32 + c * 8;
      gload_lds16(A + arow + (size_t)(r + lr) * K + k0 + lc * 8, &sA[r * 64]);
      gload_lds16(B + brow + (size_t)(r + lr) * K + k0 + lc * 8, &sB[r * 64]);
    }
    __syncthreads();
    for (int kk = 0; kk < 64; kk += 32) {
      s16x8 af[4], bf[4];
      int ro = lane & 15, ko = kk + (lane >> 4) * 8;
      for (int m = 0; m < 4; ++m) af[m] = *(const s16x8*)&sA[(wr + m * 16 + ro) * 64 + ko];
      for (int n = 0; n < 4; ++n) bf[n] = *(const s16x8*)&sB[(wc + n * 16 + ro) * 64 + ko];
      for (int m = 0; m < 4; ++m)
        for (int n = 0; n < 4; ++n)
          acc[m][n] = __builtin_amdgcn_mfma_f32_16x16x32_bf16(af[m], bf[n], acc[m][n], 0, 0, 0);
    }
  }
  // ---- fused epilogue ----
  int ro = lane & 15, rg = lane >> 4;
  int gc0 = bx * 128 + wc;            // multiple of 64; head-aligned
  int sec = gc0 >> 10;                // 0=q, 1=k, 2=v (wave-uniform)
  int h = (gc0 & 1023) >> 6;
  if (sec == 2) {
    #pragma unroll
    for (int m = 0; m < 4; ++m)
      #pragma unroll
      for (int r = 0; r < 4; ++r) {
        int row = by * 128 + wr + m * 16 + rg * 4 + r;
        int s = row & 2047, bb = row >> 11;
        u16* dst = vo + ((size_t)((bb * 16 + h) * 2048 + s)) * 64;
        #pragma unroll
        for (int n = 0; n < 4; ++n) dst[n * 16 + ro] = f2b(acc[m][n][r]);
      }
  } else {
    const float* gmm = sec ? kg : qg;
    const float* bet = sec ? kb : qb;
    float gv[4], bv[4];
    #pragma unroll
    for (int n = 0; n < 4; ++n) { gv[n] = gmm[n * 16 + ro]; bv[n] = bet[n * 16 + ro]; }
    float qscale = sec == 0 ? 0.125f : 1.0f;
    u16* base = sec == 0 ? qo : ko;
    #pragma unroll
    for (int m = 0; m < 4; ++m)
      #pragma unroll
      for (int r = 0; r < 4; ++r) {
        float v0 = acc[m][0][r], v1 = acc[m][1][r], v2 = acc[m][2][r], v3 = acc[m][3][r];
        float s1 = v0 + v1 + v2 + v3;
        float s2 = v0 * v0 + v1 * v1 + v2 * v2 + v3 * v3;
        #pragma unroll
        for (int off = 1; off < 16; off <<= 1) {
          s1 += __shfl_xor(s1, off, 64);
          s2 += __shfl_xor(s2, off, 64);
        }
        float mu = s1 * (1.f / 64.f), var = s2 * (1.f / 64.f) - mu * mu;
        float rr = rsqrtf(var + 1e-6f);
        float nrm[4];
        #pragma unroll
        for (int n = 0; n < 4; ++n) nrm[n] = (acc[m][n][r] - mu) * rr * gv[n] + bv[n];
        int row = by * 128 + wr + m * 16 + rg * 4 + r;
        int s = row & 2047, bb = row >> 11;
        const float2* tr = trig + (size_t)s * 64;
        u16* dst = base + ((size_t)((bb * 16 + h) * 2048 + s)) * 64;
        #pragma unroll
        for (int n = 0; n < 4; ++n) {
          float2 cs = tr[n * 16 + ro];
          float rot = (n < 2) ? -nrm[n + 2] : nrm[n - 2];
          dst[n * 16 + ro] = f2b((nrm[n] * cs.x + rot * cs.y) * qscale);
        }
      }
  }
}

// ---------------- V transpose: (b,h,s,dh) -> (b,h,dh,s) ----------------
__global__ __launch_bounds__(256) void transpose_v(const u16* __restrict__ vi, u16* __restrict__ vt) {
  __shared__ __align__(16) u16 tile[64][72];
  int bh = blockIdx.x >> 5, st = blockIdx.x & 31;
  int t = threadIdx.x;
  const u16* src = vi + ((size_t)bh * 2048 + st * 64) * 64;
  int r = t & 63, c = (t >> 6) * 16;
  *(s16x8*)&tile[r][c]     = *(const s16x8*)(src + r * 64 + c);
  *(s16x8*)&tile[r][c + 8] = *(const s16x8*)(src + r * 64 + c + 8);
  __syncthreads();
  int dh = t & 63, so = (t >> 6) * 16;
  alignas(16) u16 buf[16];
  #pragma unroll
  for (int j = 0; j < 16; ++j) buf[j] = tile[so + j][dh];
  u16* dst = vt + ((size_t)bh * 64 + dh) * 2048 + st * 64 + so;
  *(s16x8*)dst       = *(const s16x8*)&buf[0];
  *(s16x8*)(dst + 8) = *(const s16x8*)&buf[8];
}

// ---------------- causal flash attention: K-split + paired k-tiles ----------------
// Block (4 waves) owns strips {A=pr, B=63-pr}; wave w handles kt = w, w+4, ...
// consumed 2-at-a-time per softmax pass (softmax is k-order-free): one
// max/shfl/rescale per 64 k, 8-MFMA QK bursts, deferred per-lane lsum.
__global__ __launch_bounds__(256) void attn_fwd7(const u16* __restrict__ qp, const u16* __restrict__ kp,
                                                 const u16* __restrict__ vtp, u16* __restrict__ op) {
  __shared__ u16 sO[8][64][32];            // bf16 partials, 32 KB
  __shared__ float sM[8][32], sL[8][32];
  int bid = blockIdx.x;
  int xcd = bid & 7, j = bid >> 3;
  int bh = 4 * xcd + (j >> 5), pr = j & 31;
  int tid = threadIdx.x, w = tid >> 6, l = tid & 63;
  int ql = l & 31, h5 = l >> 5;
  const int A = pr, Bs = 63 - pr;
  int b = bh >> 4, h = bh & 15;
  const u16* qptr = qp + (size_t)bh * 2048 * 64;
  const u16* kptr = kp + (size_t)bh * 2048 * 64;
  const u16* vptr = vtp + (size_t)bh * 64 * 2048;

  s16x8 qfA[4], qfB[4];
  {
    const u16* qrA = qptr + (size_t)(A * 32 + ql) * 64 + h5 * 8;
    const u16* qrB = qptr + (size_t)(Bs * 32 + ql) * 64 + h5 * 8;
    #pragma unroll
    for (int t = 0; t < 4; ++t) { qfA[t] = *(const s16x8*)(qrA + 16 * t);
                                  qfB[t] = *(const s16x8*)(qrB + 16 * t); }
  }
  f32x16 oA0 = {}, oA1 = {}, oB0 = {}, oB1 = {};
  float mA = -INFINITY, lA = 0.f, mB = -INFINITY, lB = 0.f;

  auto qk = [&](const s16x8* qf, const s16x8* kf) {
    f32x16 s = {};
    #pragma unroll
    for (int t = 0; t < 4; ++t) s = __builtin_amdgcn_mfma_f32_32x32x16_bf16(kf[t], qf[t], s, 0, 0, 0);
    return s;
  };
  auto maskd = [&](f32x16& sc) {
    #pragma unroll
    for (int r = 0; r < 16; ++r) {
      int kloc = (r & 3) + 8 * (r >> 2) + 4 * h5;
      sc[r] = (kloc > ql) ? -INFINITY : sc[r];
    }
  };
  auto vmax = [&](const f32x16& sc) {
    float t8[8], t4[4];
    #pragma unroll
    for (int i = 0; i < 8; ++i) t8[i] = fmaxf(sc[2 * i], sc[2 * i + 1]);
    #pragma unroll
    for (int i = 0; i < 4; ++i) t4[i] = fmaxf(t8[2 * i], t8[2 * i + 1]);
    return fmaxf(fmaxf(t4[0], t4[1]), fmaxf(t4[2], t4[3]));
  };
  auto pconv = [&](const f32x16& sc, s16x8& pa0, s16x8& pa1) {
    unsigned wd[8];
    #pragma unroll
    for (int i = 0; i < 8; ++i)
      asm("v_cvt_pk_bf16_f32 %0, %1, %2" : "=v"(wd[i]) : "v"(sc[2 * i]), "v"(sc[2 * i + 1]));
    u32x2 r02 = __builtin_amdgcn_permlane32_swap(wd[0], wd[2], false, false);
    u32x2 r13 = __builtin_amdgcn_permlane32_swap(wd[1], wd[3], false, false);
    u32x2 r46 = __builtin_amdgcn_permlane32_swap(wd[4], wd[6], false, false);
    u32x2 r57 = __builtin_amdgcn_permlane32_swap(wd[5], wd[7], false, false);
    u32x4 t0v = {r02[0], r13[0], r02[1], r13[1]};
    u32x4 t1v = {r46[0], r57[0], r46[1], r57[1]};
    pa0 = __builtin_bit_cast(s16x8, t0v);
    pa1 = __builtin_bit_cast(s16x8, t1v);
  };
  // one softmax pass over one or two 32-k subtiles of the same chain
  auto soft = [&](float& m, float& lsum, f32x16& o0, f32x16& o1,
                  f32x16& sx, f32x16& sy, bool has_y,
                  const s16x8* vx, const s16x8* vy) {
    float mx = vmax(sx);
    if (has_y) mx = fmaxf(mx, vmax(sy));
    mx = fmaxf(mx, __shfl_xor(mx, 32, 64));
    if (__any(mx > m)) {
      float mn = fmaxf(m, mx);
      float al = __builtin_amdgcn_exp2f((m - mn) * LOG2E);
      #pragma unroll
      for (int r = 0; r < 16; ++r) { o0[r] *= al; o1[r] *= al; }
      lsum *= al;
      m = mn;
    }
    float rs = 0.f;
    #pragma unroll
    for (int r = 0; r < 16; ++r) {
      float p = __builtin_amdgcn_exp2f((sx[r] - m) * LOG2E);
      sx[r] = p; rs += p;
    }
    if (has_y)
      #pragma unroll
      for (int r = 0; r < 16; ++r) {
        float p = __builtin_amdgcn_exp2f((sy[r] - m) * LOG2E);
        sy[r] = p; rs += p;
      }
    lsum += rs;                        // per-lane partial; merged once at end
    s16x8 pa0, pa1;
    pconv(sx, pa0, pa1);
    o0 = __builtin_amdgcn_mfma_f32_32x32x16_bf16(vx[0], pa0, o0, 0, 0, 0);
    o0 = __builtin_amdgcn_mfma_f32_32x32x16_bf16(vx[1], pa1, o0, 0, 0, 0);
    o1 = __builtin_amdgcn_mfma_f32_32x32x16_bf16(vx[2], pa0, o1, 0, 0, 0);
    o1 = __builtin_amdgcn_mfma_f32_32x32x16_bf16(vx[3], pa1, o1, 0, 0, 0);
    if (has_y) {
      s16x8 pb0, pb1;
      pconv(sy, pb0, pb1);
      o0 = __builtin_amdgcn_mfma_f32_32x32x16_bf16(vy[0], pb0, o0, 0, 0, 0);
      o0 = __builtin_amdgcn_mfma_f32_32x32x16_bf16(vy[1], pb1, o0, 0, 0, 0);
      o1 = __builtin_amdgcn_mfma_f32_32x32x16_bf16(vy[2], pb0, o1, 0, 0, 0);
      o1 = __builtin_amdgcn_mfma_f32_32x32x16_bf16(vy[3], pb1, o1, 0, 0, 0);
    }
  };
  auto ldk = [&](s16x8* kf, int kt) {
    const u16* kr = kptr + (size_t)(kt * 32 + ql) * 64 + h5 * 8;
    #pragma unroll
    for (int t = 0; t < 4; ++t) kf[t] = *(const s16x8*)(kr + 16 * t);
  };
  auto ldv = [&](s16x8* vf, int kt) {
    const u16* vr = vptr + (size_t)ql * 2048 + kt * 32 + h5 * 8;
    vf[0] = *(const s16x8*)(vr);
    vf[1] = *(const s16x8*)(vr + 16);
    vf[2] = *(const s16x8*)(vr + 32 * 2048);
    vf[3] = *(const s16x8*)(vr + 32 * 2048 + 16);
  };

  int kt = w;
  while (kt + 4 <= Bs) {               // paired iteration: (kt, kt+4)
    s16x8 kx[4], ky[4], vx[4], vy[4];
    ldk(kx, kt); ldk(ky, kt + 4);
    ldv(vx, kt); ldv(vy, kt + 4);
    {
      f32x16 sx = qk(qfB, kx), sy = qk(qfB, ky);
      if (kt + 4 == Bs) maskd(sy);
      soft(mB, lB, oB0, oB1, sx, sy, true, vx, vy);
    }
    if (kt <= A) {
      f32x16 sx = qk(qfA, kx);
      if (kt + 4 <= A) {
        f32x16 sy = qk(qfA, ky);
        if (kt + 4 == A) maskd(sy);
        soft(mA, lA, oA0, oA1, sx, sy, true, vx, vy);
      } else {
        if (kt == A) maskd(sx);
        soft(mA, lA, oA0, oA1, sx, sx, false, vx, vx);
      }
    }
    kt += 8;
  }
  if (kt <= Bs) {                      // at most one leftover tile
    s16x8 kx[4], vx[4];
    ldk(kx, kt); ldv(vx, kt);
    f32x16 sx = qk(qfB, kx);
    if (kt == Bs) maskd(sx);
    soft(mB, lB, oB0, oB1, sx, sx, false, vx, vx);
    if (kt <= A) {
      f32x16 sa = qk(qfA, kx);
      if (kt == A) maskd(sa);
      soft(mA, lA, oA0, oA1, sa, sa, false, vx, vx);
    }
  }
  lA += __shfl_xor(lA, 32, 64);
  lB += __shfl_xor(lB, 32, 64);

  // ---- write partials (bf16 staging) ----
  if (h5 == 0) {
    sM[w * 2 + 0][ql] = mA; sL[w * 2 + 0][ql] = lA;
    sM[w * 2 + 1][ql] = mB; sL[w * 2 + 1][ql] = lB;
  }
  #pragma unroll
  for (int r = 0; r < 16; ++r) {
    int dh = (r & 3) + 8 * (r >> 2) + 4 * h5;
    sO[w * 2 + 0][dh][ql]      = f2b(oA0[r]);
    sO[w * 2 + 0][dh + 32][ql] = f2b(oA1[r]);
    sO[w * 2 + 1][dh][ql]      = f2b(oB0[r]);
    sO[w * 2 + 1][dh + 32][ql] = f2b(oB1[r]);
  }
  __syncthreads();

  // ---- LSE merge + output ----
  {
    int q = tid & 31, dg = tid >> 5;
    #pragma unroll
    for (int s = 0; s < 2; ++s) {
      float m0 = sM[0 * 2 + s][q], m1 = sM[1 * 2 + s][q];
      float m2 = sM[2 * 2 + s][q], m3 = sM[3 * 2 + s][q];
      float mg = fmaxf(fmaxf(m0, m1), fmaxf(m2, m3));
      float e0 = __builtin_amdgcn_exp2f((m0 - mg) * LOG2E);
      float e1 = __builtin_amdgcn_exp2f((m1 - mg) * LOG2E);
      float e2 = __builtin_amdgcn_exp2f((m2 - mg) * LOG2E);
      float e3 = __builtin_amdgcn_exp2f((m3 - mg) * LOG2E);
      float lg = e0 * sL[0 * 2 + s][q] + e1 * sL[1 * 2 + s][q]
               + e2 * sL[2 * 2 + s][q] + e3 * sL[3 * 2 + s][q];
      float inv = 1.f / lg;
      alignas(16) u16 ob[8];
      #pragma unroll
      for (int jj = 0; jj < 8; ++jj) {
        int dh = dg * 8 + jj;
        float acc = e0 * b2f(sO[0 * 2 + s][dh][q]) + e1 * b2f(sO[1 * 2 + s][dh][q])
                  + e2 * b2f(sO[2 * 2 + s][dh][q]) + e3 * b2f(sO[3 * 2 + s][dh][q]);
        ob[jj] = f2b(acc * inv);
      }
      int q0s = (s ? Bs : A) * 32;
      u16* dst = op + ((size_t)(b * 2048 + q0s + q)) * 1024 + h * 64 + dg * 8;
      *(u16x4*)dst       = *(const u16x4*)&ob[0];
      *(u16x4*)(dst + 4) = *(const u16x4*)&ob[4];
    }
  }
}

extern "C" void kernel_launch(void* const* d_in, const int* in_sizes, int n_in,
                              void* d_out, int out_size, void* d_ws, size_t ws_size,
                              hipStream_t stream) {
  const float* x     = (const float*)d_in[0];
  const float* freqs = (const float*)d_in[2];
  const float* Wqkv  = (const float*)d_in[3];
  const float* Wout  = (const float*)d_in[4];
  const float* qg    = (const float*)d_in[5];
  const float* qb    = (const float*)d_in[6];
  const float* kg    = (const float*)d_in[7];
  const float* kb    = (const float*)d_in[8];
  float* out = (float*)d_out;

  u16* xb    = (u16*)d_ws;                 // 4,194,304 u16
  u16* wqkvb = xb + 4194304;               // 3,145,728
  u16* woutb = wqkvb + 3145728;            // 1,048,576
  float2* trig2 = (float2*)(woutb + 1048576);  // 131,072 float2 (1 MB, 16 MB-aligned base)
  u16* qo = (u16*)(trig2 + 131072);        // 4,194,304 each
  u16* ko = qo + 4194304;
  u16* vo = ko + 4194304;
  u16* ao = vo + 4194304;
  u16* vt = ao + 4194304;

  cvt_bf16<<<(4194304 + 255) / 256, 256, 0, stream>>>(x, xb, 4194304);
  cvt_bf16<<<(3145728 + 255) / 256, 256, 0, stream>>>(Wqkv, wqkvb, 3145728);
  cvt_bf16<<<(1048576 + 255) / 256, 256, 0, stream>>>(Wout, woutb, 1048576);
  trig2_tab<<<(131072 + 255) / 256, 256, 0, stream>>>(freqs, trig2, 131072);

  gemm_qkv_lnrope<<<24 * 32, 256, 0, stream>>>(xb, wqkvb, trig2, qg, qb, kg, kb, qo, ko, vo);
  transpose_v<<<32 * 32, 256, 0, stream>>>(vo, vt);
  attn_fwd7<<<1024, 256, 0, stream>>>(qo, ko, vt, ao);
  gemm_bt<<<(4096 / 128) * (1024 / 128), 256, 0, stream>>>(ao, woutb, out, 4096, 1024, 1024);
}

// Round 11
// 238.477 us; speedup vs baseline: 1.3464x; 1.0612x over previous
//
#include <hip/hip_runtime.h>
#include <hip/hip_bf16.h>
#include <cstdint>

typedef unsigned short u16;
typedef __attribute__((ext_vector_type(8))) short s16x8;
typedef __attribute__((ext_vector_type(4))) float f32x4;
typedef __attribute__((ext_vector_type(16))) float f32x16;
typedef __attribute__((ext_vector_type(4))) unsigned int u32x4;
typedef __attribute__((ext_vector_type(2))) unsigned int u32x2;
typedef __attribute__((ext_vector_type(4))) u16 u16x4;

#define LOG2E 1.44269504088896340736f

__device__ __forceinline__ u16 f2b(float f) {
  union { float f; unsigned u; } v; v.f = f;
  unsigned r = v.u + 0x7FFF + ((v.u >> 16) & 1);
  return (u16)(r >> 16);
}

__device__ __forceinline__ float b2f(u16 u) {
  union { unsigned u; float f; } v; v.u = ((unsigned)u) << 16;
  return v.f;
}

__device__ __forceinline__ void gload_lds16(const u16* g, u16* l) {
  __builtin_amdgcn_global_load_lds((const __attribute__((address_space(1))) void*)g,
                                   (__attribute__((address_space(3))) void*)l, 16, 0, 0);
}

// ---------------- fused prologue: all converts + trig table, one kernel ----------------
// float4 regions: x 1048576, wqkv 786432, wout 262144 (f4 units); then trig 131072 scalar.
__global__ __launch_bounds__(256) void prep(const float* __restrict__ x, const float* __restrict__ wqkv,
                                            const float* __restrict__ wout, const float* __restrict__ freqs,
                                            u16* __restrict__ xb, u16* __restrict__ wqkvb,
                                            u16* __restrict__ woutb, float2* __restrict__ trig) {
  const int N1 = 1048576, N2 = 786432, N3 = 262144, NT = 131072;
  const int TOT = N1 + N2 + N3 + NT;
  for (int i = blockIdx.x * 256 + threadIdx.x; i < TOT; i += gridDim.x * 256) {
    if (i < N1 + N2 + N3) {
      const float4* src; u16* dst; int j = i;
      if (i < N1)            { src = (const float4*)x;    dst = xb; }
      else if (i < N1 + N2)  { src = (const float4*)wqkv; dst = wqkvb; j = i - N1; }
      else                   { src = (const float4*)wout; dst = woutb; j = i - N1 - N2; }
      float4 v = src[j];
      u16x4 o = { f2b(v.x), f2b(v.y), f2b(v.z), f2b(v.w) };
      *(u16x4*)(dst + 4 * j) = o;
    } else {
      int j = i - (N1 + N2 + N3);
      float f = freqs[j];
      trig[j] = make_float2(cosf(f), sinf(f));
    }
  }
}

// ---------------- GEMM: C[M,N] = A[M,K] * B[N,K]^T (bf16 in, f32 out) ----------------
__global__ __launch_bounds__(256) void gemm_bt(const u16* __restrict__ A, const u16* __restrict__ B,
                                               float* __restrict__ C, int M, int N, int K) {
  __shared__ u16 sA[128 * 64];
  __shared__ u16 sB[128 * 64];
  const int nbn = N >> 7;
  int nwg = gridDim.x;
  int swz = (blockIdx.x & 7) * (nwg >> 3) + (blockIdx.x >> 3);   // XCD swizzle (nwg%8==0)
  int bx = swz % nbn, by = swz / nbn;
  int tid = threadIdx.x, w = tid >> 6, lane = tid & 63;
  int wr = (w >> 1) * 64, wc = (w & 1) * 64;
  int lr = lane >> 3, lc = lane & 7;
  f32x4 acc[4][4] = {};
  size_t arow = (size_t)(by * 128) * K;
  size_t brow = (size_t)(bx * 128) * K;
  for (int k0 = 0; k0 < K; k0 += 64) {
    __syncthreads();
    for (int c = 0; c < 4; ++c) {
      int r = w * 32 + c * 8;
      gload_lds16(A + arow + (size_t)(r + lr) * K + k0 + lc * 8, &sA[r * 64]);
      gload_lds16(B + brow + (size_t)(r + lr) * K + k0 + lc * 8, &sB[r * 64]);
    }
    __syncthreads();
    for (int kk = 0; kk < 64; kk += 32) {
      s16x8 af[4], bf[4];
      int ro = lane & 15, ko = kk + (lane >> 4) * 8;
      for (int m = 0; m < 4; ++m) af[m] = *(const s16x8*)&sA[(wr + m * 16 + ro) * 64 + ko];
      for (int n = 0; n < 4; ++n) bf[n] = *(const s16x8*)&sB[(wc + n * 16 + ro) * 64 + ko];
      for (int m = 0; m < 4; ++m)
        for (int n = 0; n < 4; ++n)
          acc[m][n] = __builtin_amdgcn_mfma_f32_16x16x32_bf16(af[m], bf[n], acc[m][n], 0, 0, 0);
    }
  }
  int ro = lane & 15, rg = lane >> 4;
  for (int m = 0; m < 4; ++m)
    for (int n = 0; n < 4; ++n) {
      int row = by * 128 + wr + m * 16 + rg * 4;
      int col = bx * 128 + wc + n * 16 + ro;
      float* cp = C + (size_t)row * N + col;
      for (int r = 0; r < 4; ++r) cp[(size_t)r * N] = acc[m][n][r];
    }
}

// ---------------- fused QKV GEMM + per-head LN + RoPE + bf16 q/k/v write -------------
__global__ __launch_bounds__(256) void gemm_qkv_lnrope(
    const u16* __restrict__ A, const u16* __restrict__ B, const float2* __restrict__ trig,
    const float* __restrict__ qg, const float* __restrict__ qb,
    const float* __restrict__ kg, const float* __restrict__ kb,
    u16* __restrict__ qo, u16* __restrict__ ko, u16* __restrict__ vo) {
  const int K = 1024;
  __shared__ u16 sA[128 * 64];
  __shared__ u16 sB[128 * 64];
  int nwg = gridDim.x;
  int swz = (blockIdx.x & 7) * (nwg >> 3) + (blockIdx.x >> 3);   // XCD swizzle (768%8==0)
  int bx = swz % 24, by = swz / 24;
  int tid = threadIdx.x, w = tid >> 6, lane = tid & 63;
  int wr = (w >> 1) * 64, wc = (w & 1) * 64;
  int lr = lane >> 3, lc = lane & 7;
  f32x4 acc[4][4] = {};
  size_t arow = (size_t)(by * 128) * K;
  size_t brow = (size_t)(bx * 128) * K;
  for (int k0 = 0; k0 < K; k0 += 64) {
    __syncthreads();
    for (int c = 0; c < 4; ++c) {
      int r = w * 32 + c * 8;
      gload_lds16(A + arow + (size_t)(r + lr) * K + k0 + lc * 8, &sA[r * 64]);
      gload_lds16(B + brow + (size_t)(r + lr) * K + k0 + lc * 8, &sB[r * 64]);
    }
    __syncthreads();
    for (int kk = 0; kk < 64; kk += 32) {
      s16x8 af[4], bf[4];
      int ro = lane & 15, ko = kk + (lane >> 4) * 8;
      for (int m = 0; m < 4; ++m) af[m] = *(const s16x8*)&sA[(wr + m * 16 + ro) * 64 + ko];
      for (int n = 0; n < 4; ++n) bf[n] = *(const s16x8*)&sB[(wc + n * 16 + ro) * 64 + ko];
      for (int m = 0; m < 4; ++m)
        for (int n = 0; n < 4; ++n)
          acc[m][n] = __builtin_amdgcn_mfma_f32_16x16x32_bf16(af[m], bf[n], acc[m][n], 0, 0, 0);
    }
  }
  // ---- fused epilogue ----
  int ro = lane & 15, rg = lane >> 4;
  int gc0 = bx * 128 + wc;            // multiple of 64; head-aligned
  int sec = gc0 >> 10;                // 0=q, 1=k, 2=v (wave-uniform)
  int h = (gc0 & 1023) >> 6;
  if (sec == 2) {
    #pragma unroll
    for (int m = 0; m < 4; ++m)
      #pragma unroll
      for (int r = 0; r < 4; ++r) {
        int row = by * 128 + wr + m * 16 + rg * 4 + r;
        int s = row & 2047, bb = row >> 11;
        u16* dst = vo + ((size_t)((bb * 16 + h) * 2048 + s)) * 64;
        #pragma unroll
        for (int n = 0; n < 4; ++n) dst[n * 16 + ro] = f2b(acc[m][n][r]);
      }
  } else {
    const float* gmm = sec ? kg : qg;
    const float* bet = sec ? kb : qb;
    float gv[4], bv[4];
    #pragma unroll
    for (int n = 0; n < 4; ++n) { gv[n] = gmm[n * 16 + ro]; bv[n] = bet[n * 16 + ro]; }
    float qscale = sec == 0 ? 0.125f : 1.0f;
    u16* base = sec == 0 ? qo : ko;
    #pragma unroll
    for (int m = 0; m < 4; ++m)
      #pragma unroll
      for (int r = 0; r < 4; ++r) {
        float v0 = acc[m][0][r], v1 = acc[m][1][r], v2 = acc[m][2][r], v3 = acc[m][3][r];
        float s1 = v0 + v1 + v2 + v3;
        float s2 = v0 * v0 + v1 * v1 + v2 * v2 + v3 * v3;
        #pragma unroll
        for (int off = 1; off < 16; off <<= 1) {
          s1 += __shfl_xor(s1, off, 64);
          s2 += __shfl_xor(s2, off, 64);
        }
        float mu = s1 * (1.f / 64.f), var = s2 * (1.f / 64.f) - mu * mu;
        float rr = rsqrtf(var + 1e-6f);
        float nrm[4];
        #pragma unroll
        for (int n = 0; n < 4; ++n) nrm[n] = (acc[m][n][r] - mu) * rr * gv[n] + bv[n];
        int row = by * 128 + wr + m * 16 + rg * 4 + r;
        int s = row & 2047, bb = row >> 11;
        const float2* tr = trig + (size_t)s * 64;
        u16* dst = base + ((size_t)((bb * 16 + h) * 2048 + s)) * 64;
        #pragma unroll
        for (int n = 0; n < 4; ++n) {
          float2 cs = tr[n * 16 + ro];
          float rot = (n < 2) ? -nrm[n + 2] : nrm[n - 2];
          dst[n * 16 + ro] = f2b((nrm[n] * cs.x + rot * cs.y) * qscale);
        }
      }
  }
}

// ---------------- V transpose: (b,h,s,dh) -> (b,h,dh,s) ----------------
__global__ __launch_bounds__(256) void transpose_v(const u16* __restrict__ vi, u16* __restrict__ vt) {
  __shared__ __align__(16) u16 tile[64][72];
  int bh = blockIdx.x >> 5, st = blockIdx.x & 31;
  int t = threadIdx.x;
  const u16* src = vi + ((size_t)bh * 2048 + st * 64) * 64;
  int r = t & 63, c = (t >> 6) * 16;
  *(s16x8*)&tile[r][c]     = *(const s16x8*)(src + r * 64 + c);
  *(s16x8*)&tile[r][c + 8] = *(const s16x8*)(src + r * 64 + c + 8);
  __syncthreads();
  int dh = t & 63, so = (t >> 6) * 16;
  alignas(16) u16 buf[16];
  #pragma unroll
  for (int j = 0; j < 16; ++j) buf[j] = tile[so + j][dh];
  u16* dst = vt + ((size_t)bh * 64 + dh) * 2048 + st * 64 + so;
  *(s16x8*)dst       = *(const s16x8*)&buf[0];
  *(s16x8*)(dst + 8) = *(const s16x8*)&buf[8];
}

// ---------------- causal flash attention: K-split flash-decode (R9 structure + T5) ----
__global__ __launch_bounds__(256) void attn_fwd8(const u16* __restrict__ qp, const u16* __restrict__ kp,
                                                 const u16* __restrict__ vtp, u16* __restrict__ op) {
  __shared__ u16 sO[8][64][32];            // bf16 partials, 32 KB
  __shared__ float sM[8][32], sL[8][32];
  int bid = blockIdx.x;
  int xcd = bid & 7, j = bid >> 3;
  int bh = 4 * xcd + (j >> 5), pr = j & 31;
  int tid = threadIdx.x, w = tid >> 6, l = tid & 63;
  int ql = l & 31, h5 = l >> 5;
  const int A = pr, Bs = 63 - pr;
  int b = bh >> 4, h = bh & 15;
  const u16* qptr = qp + (size_t)bh * 2048 * 64;
  const u16* kptr = kp + (size_t)bh * 2048 * 64;
  const u16* vptr = vtp + (size_t)bh * 64 * 2048;

  s16x8 qfA[4], qfB[4];
  {
    const u16* qrA = qptr + (size_t)(A * 32 + ql) * 64 + h5 * 8;
    const u16* qrB = qptr + (size_t)(Bs * 32 + ql) * 64 + h5 * 8;
    #pragma unroll
    for (int t = 0; t < 4; ++t) { qfA[t] = *(const s16x8*)(qrA + 16 * t);
                                  qfB[t] = *(const s16x8*)(qrB + 16 * t); }
  }
  f32x16 oA0 = {}, oA1 = {}, oB0 = {}, oB1 = {};
  float mA = -INFINITY, lA = 0.f, mB = -INFINITY, lB = 0.f;

  auto tile = [&](const s16x8* qf, float& m, float& lsum, f32x16& o0, f32x16& o1,
                  s16x8 k0, s16x8 k1, s16x8 k2, s16x8 k3,
                  s16x8 v00, s16x8 v01, s16x8 v10, s16x8 v11, int kt, int strip) {
    f32x16 sc = {};
    __builtin_amdgcn_s_setprio(1);
    sc = __builtin_amdgcn_mfma_f32_32x32x16_bf16(k0, qf[0], sc, 0, 0, 0);
    sc = __builtin_amdgcn_mfma_f32_32x32x16_bf16(k1, qf[1], sc, 0, 0, 0);
    sc = __builtin_amdgcn_mfma_f32_32x32x16_bf16(k2, qf[2], sc, 0, 0, 0);
    sc = __builtin_amdgcn_mfma_f32_32x32x16_bf16(k3, qf[3], sc, 0, 0, 0);
    __builtin_amdgcn_s_setprio(0);

    if (kt == strip) {   // diagonal tile: mask k_loc > q_loc
      #pragma unroll
      for (int r = 0; r < 16; ++r) {
        int kloc = (r & 3) + 8 * (r >> 2) + 4 * h5;
        sc[r] = (kloc > ql) ? -INFINITY : sc[r];
      }
    }
    float t8[8], t4[4];
    #pragma unroll
    for (int i = 0; i < 8; ++i) t8[i] = fmaxf(sc[2 * i], sc[2 * i + 1]);
    #pragma unroll
    for (int i = 0; i < 4; ++i) t4[i] = fmaxf(t8[2 * i], t8[2 * i + 1]);
    float mx = fmaxf(fmaxf(t4[0], t4[1]), fmaxf(t4[2], t4[3]));
    mx = fmaxf(mx, __shfl_xor(mx, 32, 64));

    if (__any(mx > m)) {          // exact skip: alpha==1.0 when no lane grows
      float mn = fmaxf(m, mx);
      float alpha = __builtin_amdgcn_exp2f((m - mn) * LOG2E);
      #pragma unroll
      for (int r = 0; r < 16; ++r) { o0[r] *= alpha; o1[r] *= alpha; }
      lsum *= alpha;
      m = mn;
    }
    float rs = 0.f;
    #pragma unroll
    for (int r = 0; r < 16; ++r) {
      float p = __builtin_amdgcn_exp2f((sc[r] - m) * LOG2E);
      sc[r] = p; rs += p;
    }
    rs += __shfl_xor(rs, 32, 64);
    lsum += rs;

    unsigned wd[8];
    #pragma unroll
    for (int i = 0; i < 8; ++i)
      asm("v_cvt_pk_bf16_f32 %0, %1, %2" : "=v"(wd[i]) : "v"(sc[2 * i]), "v"(sc[2 * i + 1]));
    u32x2 r02 = __builtin_amdgcn_permlane32_swap(wd[0], wd[2], false, false);
    u32x2 r13 = __builtin_amdgcn_permlane32_swap(wd[1], wd[3], false, false);
    u32x2 r46 = __builtin_amdgcn_permlane32_swap(wd[4], wd[6], false, false);
    u32x2 r57 = __builtin_amdgcn_permlane32_swap(wd[5], wd[7], false, false);
    u32x4 t0v = {r02[0], r13[0], r02[1], r13[1]};
    u32x4 t1v = {r46[0], r57[0], r46[1], r57[1]};
    s16x8 pa0 = __builtin_bit_cast(s16x8, t0v);
    s16x8 pa1 = __builtin_bit_cast(s16x8, t1v);

    __builtin_amdgcn_s_setprio(1);
    o0 = __builtin_amdgcn_mfma_f32_32x32x16_bf16(v00, pa0, o0, 0, 0, 0);
    o0 = __builtin_amdgcn_mfma_f32_32x32x16_bf16(v01, pa1, o0, 0, 0, 0);
    o1 = __builtin_amdgcn_mfma_f32_32x32x16_bf16(v10, pa0, o1, 0, 0, 0);
    o1 = __builtin_amdgcn_mfma_f32_32x32x16_bf16(v11, pa1, o1, 0, 0, 0);
    __builtin_amdgcn_s_setprio(0);
  };

  for (int kt = w; kt <= Bs; kt += 4) {
    const u16* kr = kptr + (size_t)(kt * 32 + ql) * 64 + h5 * 8;
    s16x8 k0 = *(const s16x8*)(kr);
    s16x8 k1 = *(const s16x8*)(kr + 16);
    s16x8 k2 = *(const s16x8*)(kr + 32);
    s16x8 k3 = *(const s16x8*)(kr + 48);
    const u16* vr = vptr + (size_t)ql * 2048 + kt * 32 + h5 * 8;
    s16x8 v00 = *(const s16x8*)(vr);
    s16x8 v01 = *(const s16x8*)(vr + 16);
    s16x8 v10 = *(const s16x8*)(vr + 32 * 2048);
    s16x8 v11 = *(const s16x8*)(vr + 32 * 2048 + 16);

    tile(qfB, mB, lB, oB0, oB1, k0, k1, k2, k3, v00, v01, v10, v11, kt, Bs);
    if (kt <= A)
      tile(qfA, mA, lA, oA0, oA1, k0, k1, k2, k3, v00, v01, v10, v11, kt, A);
  }

  // ---- write partials (bf16 staging; accumulators die here) ----
  if (h5 == 0) {
    sM[w * 2 + 0][ql] = mA; sL[w * 2 + 0][ql] = lA;
    sM[w * 2 + 1][ql] = mB; sL[w * 2 + 1][ql] = lB;
  }
  #pragma unroll
  for (int r = 0; r < 16; ++r) {
    int dh = (r & 3) + 8 * (r >> 2) + 4 * h5;
    sO[w * 2 + 0][dh][ql]      = f2b(oA0[r]);
    sO[w * 2 + 0][dh + 32][ql] = f2b(oA1[r]);
    sO[w * 2 + 1][dh][ql]      = f2b(oB0[r]);
    sO[w * 2 + 1][dh + 32][ql] = f2b(oB1[r]);
  }
  __syncthreads();

  // ---- LSE merge + output ----
  {
    int q = tid & 31, dg = tid >> 5;   // dg 0..7
    #pragma unroll
    for (int s = 0; s < 2; ++s) {
      float m0 = sM[0 * 2 + s][q], m1 = sM[1 * 2 + s][q];
      float m2 = sM[2 * 2 + s][q], m3 = sM[3 * 2 + s][q];
      float mg = fmaxf(fmaxf(m0, m1), fmaxf(m2, m3));
      float e0 = __builtin_amdgcn_exp2f((m0 - mg) * LOG2E);
      float e1 = __builtin_amdgcn_exp2f((m1 - mg) * LOG2E);
      float e2 = __builtin_amdgcn_exp2f((m2 - mg) * LOG2E);
      float e3 = __builtin_amdgcn_exp2f((m3 - mg) * LOG2E);
      float lg = e0 * sL[0 * 2 + s][q] + e1 * sL[1 * 2 + s][q]
               + e2 * sL[2 * 2 + s][q] + e3 * sL[3 * 2 + s][q];
      float inv = 1.f / lg;
      alignas(16) u16 ob[8];
      #pragma unroll
      for (int jj = 0; jj < 8; ++jj) {
        int dh = dg * 8 + jj;
        float acc = e0 * b2f(sO[0 * 2 + s][dh][q]) + e1 * b2f(sO[1 * 2 + s][dh][q])
                  + e2 * b2f(sO[2 * 2 + s][dh][q]) + e3 * b2f(sO[3 * 2 + s][dh][q]);
        ob[jj] = f2b(acc * inv);
      }
      int q0s = (s ? Bs : A) * 32;
      u16* dst = op + ((size_t)(b * 2048 + q0s + q)) * 1024 + h * 64 + dg * 8;
      *(u16x4*)dst       = *(const u16x4*)&ob[0];
      *(u16x4*)(dst + 4) = *(const u16x4*)&ob[4];
    }
  }
}

extern "C" void kernel_launch(void* const* d_in, const int* in_sizes, int n_in,
                              void* d_out, int out_size, void* d_ws, size_t ws_size,
                              hipStream_t stream) {
  const float* x     = (const float*)d_in[0];
  const float* freqs = (const float*)d_in[2];
  const float* Wqkv  = (const float*)d_in[3];
  const float* Wout  = (const float*)d_in[4];
  const float* qg    = (const float*)d_in[5];
  const float* qb    = (const float*)d_in[6];
  const float* kg    = (const float*)d_in[7];
  const float* kb    = (const float*)d_in[8];
  float* out = (float*)d_out;

  u16* xb    = (u16*)d_ws;                 // 4,194,304 u16
  u16* wqkvb = xb + 4194304;               // 3,145,728
  u16* woutb = wqkvb + 3145728;            // 1,048,576
  float2* trig2 = (float2*)(woutb + 1048576);  // 131,072 float2
  u16* qo = (u16*)(trig2 + 131072);        // 4,194,304 each
  u16* ko = qo + 4194304;
  u16* vo = ko + 4194304;
  u16* ao = vo + 4194304;
  u16* vt = ao + 4194304;

  prep<<<2048, 256, 0, stream>>>(x, Wqkv, Wout, freqs, xb, wqkvb, woutb, trig2);
  gemm_qkv_lnrope<<<24 * 32, 256, 0, stream>>>(xb, wqkvb, trig2, qg, qb, kg, kb, qo, ko, vo);
  transpose_v<<<32 * 32, 256, 0, stream>>>(vo, vt);
  attn_fwd8<<<1024, 256, 0, stream>>>(qo, ko, vt, ao);
  gemm_bt<<<(4096 / 128) * (1024 / 128), 256, 0, stream>>>(ao, woutb, out, 4096, 1024, 1024);
}